// Round 11
// baseline (190.224 us; speedup 1.0000x reference)
//
#include <hip/hip_runtime.h>
#include <hip/hip_fp16.h>

#define NB     384           // 6 waves; 1152 = 384*3 -> 3 rows/thread
#define ROWS   3
#define N_ROUTE 1152
#define RB     18            // row-blocks of 64 rows
#define NCHUNK 16            // uint4 chunks per row in Wh layout

typedef __fp16 half2v __attribute__((ext_vector_type(2)));

__device__ __forceinline__ float fdot2u(unsigned int a, unsigned int b, float c) {
#if __has_builtin(__builtin_amdgcn_fdot2)
    half2v ha, hb;
    __builtin_memcpy(&ha, &a, 4);
    __builtin_memcpy(&hb, &b, 4);
    return __builtin_amdgcn_fdot2(ha, hb, c, false);
#else
    const __half2 h_a = *reinterpret_cast<const __half2*>(&a);
    const __half2 h_b = *reinterpret_cast<const __half2*>(&b);
    return fmaf(__low2float(h_a), __low2float(h_b),
           fmaf(__high2float(h_a), __high2float(h_b), c));
#endif
}

__device__ __forceinline__ unsigned int pkh(float a, float b) {
    half2v h = __builtin_amdgcn_cvt_pkrtz(a, b);
    unsigned int u;
    __builtin_memcpy(&u, &h, 4);
    return u;
}

template<int CTRL>
__device__ __forceinline__ float dpp_add(float v) {
    int t = __builtin_amdgcn_update_dpp(0, __float_as_int(v), CTRL, 0xF, 0xF, true);
    return v + __int_as_float(t);
}
// 4-step DPP: per-16-lane-group sums land in lanes 15/31/47/63.
__device__ __forceinline__ float wave_sum15(float v) {
    v = dpp_add<0x111>(v);   // row_shr:1
    v = dpp_add<0x112>(v);   // row_shr:2
    v = dpp_add<0x114>(v);   // row_shr:4
    v = dpp_add<0x118>(v);   // row_shr:8
    return v;
}

// ---- Pre-pass: W fp32 -> fp16, per-thread-coalesced layout (wide version) ----
// Wh[((c*18+r)*16 + o)*64 + l] = uint4 of 4 half2 i-pairs of W[c][r*64+l][i][o].
// One thread per chunk; reads & writes fully coalesced.
__global__ __launch_bounds__(256, 4)
void convert_w(const float* __restrict__ W, uint4* __restrict__ Wh)
{
    const int tid  = blockIdx.x * 256 + threadIdx.x;   // 184320 = 180*64*16
    const int o    = tid & 15;
    const int rest = tid >> 4;
    const int l    = rest & 63;
    const int cr   = rest >> 6;                        // c*18 + r
    const float* __restrict__ src = W + ((size_t)cr * 64 + l) * 128 + o;
    float f[8];
    #pragma unroll
    for (int i = 0; i < 8; ++i) f[i] = src[i * 16];
    uint4 v;
    v.x = pkh(f[0], f[1]);
    v.y = pkh(f[2], f[3]);
    v.z = pkh(f[4], f[5]);
    v.w = pkh(f[6], f[7]);
    Wh[((size_t)cr * 16 + o) * 64 + l] = v;
}

// ---- Main kernel: register-P, 2 batches per block (one W read, 2x compute) ----
__global__ __launch_bounds__(NB, 2)
void capsule_routing_reg2(const float* __restrict__ x,
                          const uint4* __restrict__ Wh,
                          float* __restrict__ out)
{
    __shared__ float red[6][4][36];   // [wave][quad][bt*18 + (16 s, Z)]
    __shared__ float vfin[2][16];

    const int t    = threadIdx.x;
    const int lane = t & 63;
    const int wid  = t >> 6;
    const int bid  = blockIdx.x;
    const int c    = bid >> 7;
    const int b0   = (bid & 127) << 1;     // batches b0, b0+1

    // ---- P-build: rows n = 64*(wid+6k)+lane; one W read feeds both batches ----
    unsigned int p2[2][ROWS][8];
    {
        const float* __restrict__ xA = x + (size_t)b0 * (N_ROUTE * 8);
        const float* __restrict__ xB = xA + N_ROUTE * 8;
        const uint4* __restrict__ Wc = Wh + (size_t)c * RB * NCHUNK * 64;
        #pragma unroll
        for (int k = 0; k < ROWS; ++k) {
            const int r = wid + 6 * k;
            const int n = (r << 6) + lane;
            const float4 a0 = *reinterpret_cast<const float4*>(xA + n * 8);
            const float4 a1 = *reinterpret_cast<const float4*>(xA + n * 8 + 4);
            const float4 c0 = *reinterpret_cast<const float4*>(xB + n * 8);
            const float4 c1 = *reinterpret_cast<const float4*>(xB + n * 8 + 4);
            const unsigned int xhA[4] = { pkh(a0.x, a0.y), pkh(a0.z, a0.w),
                                          pkh(a1.x, a1.y), pkh(a1.z, a1.w) };
            const unsigned int xhB[4] = { pkh(c0.x, c0.y), pkh(c0.z, c0.w),
                                          pkh(c1.x, c1.y), pkh(c1.z, c1.w) };
            const uint4* __restrict__ wr = Wc + (size_t)r * NCHUNK * 64 + lane;
            #pragma unroll
            for (int j = 0; j < 8; ++j) {          // o-pair (2j, 2j+1)
                const uint4 w0 = wr[(2 * j)     * 64];
                const uint4 w1 = wr[(2 * j + 1) * 64];
                float dA0 = fdot2u(xhA[0], w0.x, 0.f);
                dA0 = fdot2u(xhA[1], w0.y, dA0);
                dA0 = fdot2u(xhA[2], w0.z, dA0);
                dA0 = fdot2u(xhA[3], w0.w, dA0);
                float dA1 = fdot2u(xhA[0], w1.x, 0.f);
                dA1 = fdot2u(xhA[1], w1.y, dA1);
                dA1 = fdot2u(xhA[2], w1.z, dA1);
                dA1 = fdot2u(xhA[3], w1.w, dA1);
                float dB0 = fdot2u(xhB[0], w0.x, 0.f);
                dB0 = fdot2u(xhB[1], w0.y, dB0);
                dB0 = fdot2u(xhB[2], w0.z, dB0);
                dB0 = fdot2u(xhB[3], w0.w, dB0);
                float dB1 = fdot2u(xhB[0], w1.x, 0.f);
                dB1 = fdot2u(xhB[1], w1.y, dB1);
                dB1 = fdot2u(xhB[2], w1.z, dB1);
                dB1 = fdot2u(xhB[3], w1.w, dB1);
                p2[0][k][j] = pkh(dA0, dA1);
                p2[1][k][j] = pkh(dB0, dB1);
            }
        }
    }
    // No barrier: each thread owns its rows.

    float lg[2][ROWS] = {{0.f, 0.f, 0.f}, {0.f, 0.f, 0.f}};
    unsigned int vph[2][8] = {{0,0,0,0,0,0,0,0}, {0,0,0,0,0,0,0,0}};

    #pragma unroll
    for (int it = 0; it < 3; ++it) {
        // bt-sequential rows-pass + reduce (keeps live VGPR set small)
        #pragma unroll
        for (int bt = 0; bt < 2; ++bt) {
            float sp[16];
            #pragma unroll
            for (int o = 0; o < 16; ++o) sp[o] = 0.f;
            float zp = (it == 0) ? (float)ROWS : 0.f;

            #pragma unroll
            for (int k = 0; k < ROWS; ++k) {
                float e;
                if (it == 0) {
                    e = 1.f;                        // softmax of zeros = uniform
                } else {
                    float d = 0.f;                  // logit += dot(P[n], v)
                    #pragma unroll
                    for (int j = 0; j < 8; ++j) d = fdot2u(p2[bt][k][j], vph[bt][j], d);
                    lg[bt][k] += d;
                    e = __expf(lg[bt][k]);          // |lg| small; no max-sub
                    zp += e;
                }
                #pragma unroll
                for (int j = 0; j < 8; ++j) {
                    const __half2 h = *reinterpret_cast<const __half2*>(&p2[bt][k][j]);
                    sp[2 * j]     = fmaf(e, __low2float(h),  sp[2 * j]);
                    sp[2 * j + 1] = fmaf(e, __high2float(h), sp[2 * j + 1]);
                }
            }

            // 17-value 4-step DPP: 16-lane group sums in lanes 15 mod 16
            #pragma unroll
            for (int o = 0; o < 16; ++o) sp[o] = wave_sum15(sp[o]);
            zp = wave_sum15(zp);
            if ((lane & 15) == 15) {
                const int q = lane >> 4;
                #pragma unroll
                for (int o = 0; o < 16; ++o) red[wid][q][bt * 18 + o] = sp[o];
                red[wid][q][bt * 18 + 16] = zp;
            }
        }
        __syncthreads();                            // barrier 1: red ready

        if (t < 32) {                               // t<16: bt0, t in 16..31: bt1
            const int bt = t >> 4, o = t & 15;
            float tot = 0.f, Zt = 0.f;
            #pragma unroll
            for (int w2 = 0; w2 < 6; ++w2)
                #pragma unroll
                for (int q = 0; q < 4; ++q) {
                    tot += red[w2][q][bt * 18 + o];
                    Zt  += red[w2][q][bt * 18 + 16];
                }
            const float so = tot / Zt;              // s[o]
            float sq = so * so;                     // 16-lane ||s||^2
            #pragma unroll
            for (int off = 8; off >= 1; off >>= 1) sq += __shfl_xor(sq, off, 16);
            const float fac = sqrtf(sq) / (1.f + sq);
            const float vo  = so * fac;
            if (it == 2) out[(((size_t)c << 8) + b0 + bt) * 16 + o] = vo;
            else         vfin[bt][o] = vo;
        }
        if (it < 2) {
            __syncthreads();                        // barrier 2: vfin ready, red safe
            #pragma unroll
            for (int bt = 0; bt < 2; ++bt) {
                const float4 v0 = *reinterpret_cast<const float4*>(&vfin[bt][0]);
                const float4 v1 = *reinterpret_cast<const float4*>(&vfin[bt][4]);
                const float4 v2 = *reinterpret_cast<const float4*>(&vfin[bt][8]);
                const float4 v3 = *reinterpret_cast<const float4*>(&vfin[bt][12]);
                vph[bt][0] = pkh(v0.x, v0.y);  vph[bt][1] = pkh(v0.z, v0.w);
                vph[bt][2] = pkh(v1.x, v1.y);  vph[bt][3] = pkh(v1.z, v1.w);
                vph[bt][4] = pkh(v2.x, v2.y);  vph[bt][5] = pkh(v2.z, v2.w);
                vph[bt][6] = pkh(v3.x, v3.y);  vph[bt][7] = pkh(v3.z, v3.w);
            }
        }
    }
}

// ---- Fallback (ws too small): R8-style fp32-W + LDS-P kernel (known-good) ----
__global__ __launch_bounds__(NB, 2)
void capsule_routing_lds(const float* __restrict__ x,
                         const float* __restrict__ W,
                         float* __restrict__ out)
{
    __shared__ unsigned int P[N_ROUTE * 8];
    __shared__ float red[6][20];
    __shared__ float vfin[16];

    const int t    = threadIdx.x;
    const int bid  = blockIdx.x;
    const int c    = bid >> 8;
    const int b    = bid & 255;
    const int lane = t & 63;
    const int wid  = t >> 6;

    {
        const int og = t & 3;
        const int nl = t >> 2;
        const float* __restrict__ xb = x + (size_t)b * (N_ROUTE * 8);
        const float* __restrict__ Wc = W + (size_t)c * (N_ROUTE * 128);
        #pragma unroll 2
        for (int pp = 0; pp < 12; ++pp) {
            const int n = pp * 96 + nl;
            const float4 x0 = *reinterpret_cast<const float4*>(xb + n * 8);
            const float4 x1 = *reinterpret_cast<const float4*>(xb + n * 8 + 4);
            const float xs[8] = {x0.x, x0.y, x0.z, x0.w, x1.x, x1.y, x1.z, x1.w};
            const float* __restrict__ wp = Wc + (size_t)n * 128 + (og << 2);
            float4 acc = make_float4(0.f, 0.f, 0.f, 0.f);
            #pragma unroll
            for (int i = 0; i < 8; ++i) {
                const float4 w = *reinterpret_cast<const float4*>(wp + i * 16);
                acc.x = fmaf(xs[i], w.x, acc.x);
                acc.y = fmaf(xs[i], w.y, acc.y);
                acc.z = fmaf(xs[i], w.z, acc.z);
                acc.w = fmaf(xs[i], w.w, acc.w);
            }
            const int s    = (n >> 2) & 7;
            const int base = n << 3;
            P[base + (((og << 1)    ) ^ s)] = pkh(acc.x, acc.y);
            P[base + (((og << 1) + 1) ^ s)] = pkh(acc.z, acc.w);
        }
    }
    __syncthreads();

    float vprev[16];
    #pragma unroll
    for (int o = 0; o < 16; ++o) vprev[o] = 0.f;
    float lg[ROWS] = {0.f, 0.f, 0.f};

    #pragma unroll
    for (int it = 0; it < 3; ++it) {
        float sp[16];
        #pragma unroll
        for (int o = 0; o < 16; ++o) sp[o] = 0.f;
        float zp = (it == 0) ? (float)ROWS : 0.f;

        #pragma unroll
        for (int k = 0; k < ROWS; ++k) {
            const int n = t + k * NB;
            const int s = (n >> 2) & 7;
            const unsigned int* __restrict__ pr = &P[n << 3];
            __half2 h[8];
            #pragma unroll
            for (int j = 0; j < 8; ++j) {
                const unsigned int w = pr[j ^ s];
                h[j] = *reinterpret_cast<const __half2*>(&w);
            }
            float e;
            if (it == 0) {
                e = 1.f;
            } else {
                float d = 0.f;
                #pragma unroll
                for (int j = 0; j < 8; ++j) {
                    d = fmaf(__low2float(h[j]),  vprev[2 * j],     d);
                    d = fmaf(__high2float(h[j]), vprev[2 * j + 1], d);
                }
                lg[k] += d;
                e = __expf(lg[k]);
                zp += e;
            }
            #pragma unroll
            for (int j = 0; j < 8; ++j) {
                sp[2 * j]     = fmaf(e, __low2float(h[j]),  sp[2 * j]);
                sp[2 * j + 1] = fmaf(e, __high2float(h[j]), sp[2 * j + 1]);
            }
        }

        #pragma unroll
        for (int o = 0; o < 16; ++o) {
            float v = wave_sum15(sp[o]);
            v = dpp_add<0x142>(v);          // row_bcast:15
            v = dpp_add<0x143>(v);          // row_bcast:31
            sp[o] = v;
        }
        {
            float v = wave_sum15(zp);
            v = dpp_add<0x142>(v);
            v = dpp_add<0x143>(v);
            zp = v;
        }
        if (lane == 63) {
            #pragma unroll
            for (int o = 0; o < 16; ++o) red[wid][o] = sp[o];
            red[wid][16] = zp;
        }
        __syncthreads();

        if (t < 16) {
            float tot = 0.f, Zt = 0.f;
            #pragma unroll
            for (int w2 = 0; w2 < 6; ++w2) { tot += red[w2][t]; Zt += red[w2][16]; }
            const float so = tot / Zt;
            float sq = so * so;
            #pragma unroll
            for (int off = 8; off >= 1; off >>= 1) sq += __shfl_xor(sq, off);
            const float fac = sqrtf(sq) / (1.f + sq);
            const float vo  = so * fac;
            if (it == 2) out[((size_t)bid << 4) + t] = vo;
            else         vfin[t] = vo;
        }
        if (it < 2) {
            __syncthreads();
            #pragma unroll
            for (int o = 0; o < 16; ++o) vprev[o] = vfin[o];
        }
    }
}

extern "C" void kernel_launch(void* const* d_in, const int* in_sizes, int n_in,
                              void* d_out, int out_size, void* d_ws, size_t ws_size,
                              hipStream_t stream)
{
    const float* x   = (const float*)d_in[0];
    const float* W   = (const float*)d_in[1];
    float*       out = (float*)d_out;
    const size_t WH_BYTES = (size_t)10 * RB * NCHUNK * 64 * sizeof(uint4);  // 2.95 MB

    if (ws_size >= WH_BYTES) {
        uint4* Wh = (uint4*)d_ws;
        convert_w<<<dim3(720), dim3(256), 0, stream>>>(W, Wh);
        capsule_routing_reg2<<<dim3(10 * 128), dim3(NB), 0, stream>>>(x, Wh, out);
    } else {
        capsule_routing_lds<<<dim3(10 * 256), dim3(NB), 0, stream>>>(x, W, out);
    }
}

// Round 12
// 189.580 us; speedup vs baseline: 1.0034x; 1.0034x over previous
//
#include <hip/hip_runtime.h>
#include <hip/hip_fp16.h>

#define NB     384           // 6 waves; 1152 = 384*3 -> 3 rows/thread
#define ROWS   3
#define N_ROUTE 1152
#define RB     18            // row-blocks of 64 rows
#define NCHUNK 16            // uint4 chunks per row in Wh layout

typedef __fp16 half2v __attribute__((ext_vector_type(2)));

__device__ __forceinline__ float fdot2u(unsigned int a, unsigned int b, float c) {
#if __has_builtin(__builtin_amdgcn_fdot2)
    half2v ha, hb;
    __builtin_memcpy(&ha, &a, 4);
    __builtin_memcpy(&hb, &b, 4);
    return __builtin_amdgcn_fdot2(ha, hb, c, false);
#else
    const __half2 h_a = *reinterpret_cast<const __half2*>(&a);
    const __half2 h_b = *reinterpret_cast<const __half2*>(&b);
    return fmaf(__low2float(h_a), __low2float(h_b),
           fmaf(__high2float(h_a), __high2float(h_b), c));
#endif
}

__device__ __forceinline__ unsigned int pkh(float a, float b) {
    half2v h = __builtin_amdgcn_cvt_pkrtz(a, b);
    unsigned int u;
    __builtin_memcpy(&u, &h, 4);
    return u;
}

template<int CTRL>
__device__ __forceinline__ float dpp_add(float v) {
    int t = __builtin_amdgcn_update_dpp(0, __float_as_int(v), CTRL, 0xF, 0xF, true);
    return v + __int_as_float(t);
}
// 4-step DPP: per-16-lane-group sums land in lanes 15/31/47/63.
__device__ __forceinline__ float wave_sum15(float v) {
    v = dpp_add<0x111>(v);   // row_shr:1
    v = dpp_add<0x112>(v);   // row_shr:2
    v = dpp_add<0x114>(v);   // row_shr:4
    v = dpp_add<0x118>(v);   // row_shr:8
    return v;
}

// ---- Pre-pass: W fp32 -> fp16, per-thread-coalesced layout ----
// Wh[((c*18+r)*16 + o)*64 + l] = uint4 of 4 half2 i-pairs of W[c][r*64+l][i][o].
__global__ __launch_bounds__(256, 4)
void convert_w(const float* __restrict__ W, uint4* __restrict__ Wh)
{
    const int tid  = blockIdx.x * 256 + threadIdx.x;   // 184320 = 180*64*16
    const int o    = tid & 15;
    const int rest = tid >> 4;
    const int l    = rest & 63;
    const int cr   = rest >> 6;                        // c*18 + r
    const float* __restrict__ src = W + ((size_t)cr * 64 + l) * 128 + o;
    float f[8];
    #pragma unroll
    for (int i = 0; i < 8; ++i) f[i] = src[i * 16];
    uint4 v;
    v.x = pkh(f[0], f[1]);
    v.y = pkh(f[2], f[3]);
    v.z = pkh(f[4], f[5]);
    v.w = pkh(f[6], f[7]);
    Wh[((size_t)cr * 16 + o) * 64 + l] = v;
}

// ---- Main kernel: register-P, 2 batches per block (one W read, 2x compute) ----
// launch_bounds(384,1): VGPR cap 256. R11's (384,2) capped at 128 and the
// ~150-reg working set spilled (WRITE_SIZE 161MB). Actual use ~150-180 still
// permits 2 blocks/CU (3 waves/SIMD) -- occupancy was never the limiter (R10:
// VGPR=64 allowed 30 waves/CU yet VALUBusy was 40%).
__global__ __launch_bounds__(NB, 1)
void capsule_routing_reg2(const float* __restrict__ x,
                          const uint4* __restrict__ Wh,
                          float* __restrict__ out)
{
    __shared__ float red[6][4][36];   // [wave][quad][bt*18 + (16 s, Z)]
    __shared__ float vfin[2][16];

    const int t    = threadIdx.x;
    const int lane = t & 63;
    const int wid  = t >> 6;
    const int bid  = blockIdx.x;
    const int c    = bid >> 7;
    const int b0   = (bid & 127) << 1;     // batches b0, b0+1

    // ---- P-build: rows n = 64*(wid+6k)+lane; one W read feeds both batches ----
    unsigned int p2[2][ROWS][8];
    {
        const float* __restrict__ xA = x + (size_t)b0 * (N_ROUTE * 8);
        const float* __restrict__ xB = xA + N_ROUTE * 8;
        const uint4* __restrict__ Wc = Wh + (size_t)c * RB * NCHUNK * 64;
        #pragma unroll
        for (int k = 0; k < ROWS; ++k) {
            const int r = wid + 6 * k;
            const int n = (r << 6) + lane;
            const float4 a0 = *reinterpret_cast<const float4*>(xA + n * 8);
            const float4 a1 = *reinterpret_cast<const float4*>(xA + n * 8 + 4);
            const float4 c0 = *reinterpret_cast<const float4*>(xB + n * 8);
            const float4 c1 = *reinterpret_cast<const float4*>(xB + n * 8 + 4);
            const unsigned int xhA[4] = { pkh(a0.x, a0.y), pkh(a0.z, a0.w),
                                          pkh(a1.x, a1.y), pkh(a1.z, a1.w) };
            const unsigned int xhB[4] = { pkh(c0.x, c0.y), pkh(c0.z, c0.w),
                                          pkh(c1.x, c1.y), pkh(c1.z, c1.w) };
            const uint4* __restrict__ wr = Wc + (size_t)r * NCHUNK * 64 + lane;
            #pragma unroll
            for (int j = 0; j < 8; ++j) {          // o-pair (2j, 2j+1)
                const uint4 w0 = wr[(2 * j)     * 64];
                const uint4 w1 = wr[(2 * j + 1) * 64];
                float dA0 = fdot2u(xhA[0], w0.x, 0.f);
                dA0 = fdot2u(xhA[1], w0.y, dA0);
                dA0 = fdot2u(xhA[2], w0.z, dA0);
                dA0 = fdot2u(xhA[3], w0.w, dA0);
                float dA1 = fdot2u(xhA[0], w1.x, 0.f);
                dA1 = fdot2u(xhA[1], w1.y, dA1);
                dA1 = fdot2u(xhA[2], w1.z, dA1);
                dA1 = fdot2u(xhA[3], w1.w, dA1);
                float dB0 = fdot2u(xhB[0], w0.x, 0.f);
                dB0 = fdot2u(xhB[1], w0.y, dB0);
                dB0 = fdot2u(xhB[2], w0.z, dB0);
                dB0 = fdot2u(xhB[3], w0.w, dB0);
                float dB1 = fdot2u(xhB[0], w1.x, 0.f);
                dB1 = fdot2u(xhB[1], w1.y, dB1);
                dB1 = fdot2u(xhB[2], w1.z, dB1);
                dB1 = fdot2u(xhB[3], w1.w, dB1);
                p2[0][k][j] = pkh(dA0, dA1);
                p2[1][k][j] = pkh(dB0, dB1);
            }
        }
    }
    // No barrier: each thread owns its rows.

    float lg[2][ROWS] = {{0.f, 0.f, 0.f}, {0.f, 0.f, 0.f}};
    unsigned int vph[2][8] = {{0,0,0,0,0,0,0,0}, {0,0,0,0,0,0,0,0}};

    #pragma unroll
    for (int it = 0; it < 3; ++it) {
        // bt-sequential rows-pass + reduce (keeps live VGPR set small)
        #pragma unroll
        for (int bt = 0; bt < 2; ++bt) {
            float sp[16];
            #pragma unroll
            for (int o = 0; o < 16; ++o) sp[o] = 0.f;
            float zp = (it == 0) ? (float)ROWS : 0.f;

            #pragma unroll
            for (int k = 0; k < ROWS; ++k) {
                float e;
                if (it == 0) {
                    e = 1.f;                        // softmax of zeros = uniform
                } else {
                    float d = 0.f;                  // logit += dot(P[n], v)
                    #pragma unroll
                    for (int j = 0; j < 8; ++j) d = fdot2u(p2[bt][k][j], vph[bt][j], d);
                    lg[bt][k] += d;
                    e = __expf(lg[bt][k]);          // |lg| small; no max-sub
                    zp += e;
                }
                #pragma unroll
                for (int j = 0; j < 8; ++j) {
                    const __half2 h = *reinterpret_cast<const __half2*>(&p2[bt][k][j]);
                    sp[2 * j]     = fmaf(e, __low2float(h),  sp[2 * j]);
                    sp[2 * j + 1] = fmaf(e, __high2float(h), sp[2 * j + 1]);
                }
            }

            // 17-value 4-step DPP: 16-lane group sums in lanes 15 mod 16
            #pragma unroll
            for (int o = 0; o < 16; ++o) sp[o] = wave_sum15(sp[o]);
            zp = wave_sum15(zp);
            if ((lane & 15) == 15) {
                const int q = lane >> 4;
                #pragma unroll
                for (int o = 0; o < 16; ++o) red[wid][q][bt * 18 + o] = sp[o];
                red[wid][q][bt * 18 + 16] = zp;
            }
        }
        __syncthreads();                            // barrier 1: red ready

        if (t < 32) {                               // t<16: bt0, t in 16..31: bt1
            const int bt = t >> 4, o = t & 15;
            float tot = 0.f, Zt = 0.f;
            #pragma unroll
            for (int w2 = 0; w2 < 6; ++w2)
                #pragma unroll
                for (int q = 0; q < 4; ++q) {
                    tot += red[w2][q][bt * 18 + o];
                    Zt  += red[w2][q][bt * 18 + 16];
                }
            const float so = tot / Zt;              // s[o]
            float sq = so * so;                     // 16-lane ||s||^2
            #pragma unroll
            for (int off = 8; off >= 1; off >>= 1) sq += __shfl_xor(sq, off, 16);
            const float fac = sqrtf(sq) / (1.f + sq);
            const float vo  = so * fac;
            if (it == 2) out[(((size_t)c << 8) + b0 + bt) * 16 + o] = vo;
            else         vfin[bt][o] = vo;
        }
        if (it < 2) {
            __syncthreads();                        // barrier 2: vfin ready, red safe
            #pragma unroll
            for (int bt = 0; bt < 2; ++bt) {
                const float4 v0 = *reinterpret_cast<const float4*>(&vfin[bt][0]);
                const float4 v1 = *reinterpret_cast<const float4*>(&vfin[bt][4]);
                const float4 v2 = *reinterpret_cast<const float4*>(&vfin[bt][8]);
                const float4 v3 = *reinterpret_cast<const float4*>(&vfin[bt][12]);
                vph[bt][0] = pkh(v0.x, v0.y);  vph[bt][1] = pkh(v0.z, v0.w);
                vph[bt][2] = pkh(v1.x, v1.y);  vph[bt][3] = pkh(v1.z, v1.w);
                vph[bt][4] = pkh(v2.x, v2.y);  vph[bt][5] = pkh(v2.z, v2.w);
                vph[bt][6] = pkh(v3.x, v3.y);  vph[bt][7] = pkh(v3.z, v3.w);
            }
        }
    }
}

// ---- Fallback (ws too small): R8-style fp32-W + LDS-P kernel (known-good) ----
__global__ __launch_bounds__(NB, 2)
void capsule_routing_lds(const float* __restrict__ x,
                         const float* __restrict__ W,
                         float* __restrict__ out)
{
    __shared__ unsigned int P[N_ROUTE * 8];
    __shared__ float red[6][20];
    __shared__ float vfin[16];

    const int t    = threadIdx.x;
    const int bid  = blockIdx.x;
    const int c    = bid >> 8;
    const int b    = bid & 255;
    const int lane = t & 63;
    const int wid  = t >> 6;

    {
        const int og = t & 3;
        const int nl = t >> 2;
        const float* __restrict__ xb = x + (size_t)b * (N_ROUTE * 8);
        const float* __restrict__ Wc = W + (size_t)c * (N_ROUTE * 128);
        #pragma unroll 2
        for (int pp = 0; pp < 12; ++pp) {
            const int n = pp * 96 + nl;
            const float4 x0 = *reinterpret_cast<const float4*>(xb + n * 8);
            const float4 x1 = *reinterpret_cast<const float4*>(xb + n * 8 + 4);
            const float xs[8] = {x0.x, x0.y, x0.z, x0.w, x1.x, x1.y, x1.z, x1.w};
            const float* __restrict__ wp = Wc + (size_t)n * 128 + (og << 2);
            float4 acc = make_float4(0.f, 0.f, 0.f, 0.f);
            #pragma unroll
            for (int i = 0; i < 8; ++i) {
                const float4 w = *reinterpret_cast<const float4*>(wp + i * 16);
                acc.x = fmaf(xs[i], w.x, acc.x);
                acc.y = fmaf(xs[i], w.y, acc.y);
                acc.z = fmaf(xs[i], w.z, acc.z);
                acc.w = fmaf(xs[i], w.w, acc.w);
            }
            const int s    = (n >> 2) & 7;
            const int base = n << 3;
            P[base + (((og << 1)    ) ^ s)] = pkh(acc.x, acc.y);
            P[base + (((og << 1) + 1) ^ s)] = pkh(acc.z, acc.w);
        }
    }
    __syncthreads();

    float vprev[16];
    #pragma unroll
    for (int o = 0; o < 16; ++o) vprev[o] = 0.f;
    float lg[ROWS] = {0.f, 0.f, 0.f};

    #pragma unroll
    for (int it = 0; it < 3; ++it) {
        float sp[16];
        #pragma unroll
        for (int o = 0; o < 16; ++o) sp[o] = 0.f;
        float zp = (it == 0) ? (float)ROWS : 0.f;

        #pragma unroll
        for (int k = 0; k < ROWS; ++k) {
            const int n = t + k * NB;
            const int s = (n >> 2) & 7;
            const unsigned int* __restrict__ pr = &P[n << 3];
            __half2 h[8];
            #pragma unroll
            for (int j = 0; j < 8; ++j) {
                const unsigned int w = pr[j ^ s];
                h[j] = *reinterpret_cast<const __half2*>(&w);
            }
            float e;
            if (it == 0) {
                e = 1.f;
            } else {
                float d = 0.f;
                #pragma unroll
                for (int j = 0; j < 8; ++j) {
                    d = fmaf(__low2float(h[j]),  vprev[2 * j],     d);
                    d = fmaf(__high2float(h[j]), vprev[2 * j + 1], d);
                }
                lg[k] += d;
                e = __expf(lg[k]);
                zp += e;
            }
            #pragma unroll
            for (int j = 0; j < 8; ++j) {
                sp[2 * j]     = fmaf(e, __low2float(h[j]),  sp[2 * j]);
                sp[2 * j + 1] = fmaf(e, __high2float(h[j]), sp[2 * j + 1]);
            }
        }

        #pragma unroll
        for (int o = 0; o < 16; ++o) {
            float v = wave_sum15(sp[o]);
            v = dpp_add<0x142>(v);          // row_bcast:15
            v = dpp_add<0x143>(v);          // row_bcast:31
            sp[o] = v;
        }
        {
            float v = wave_sum15(zp);
            v = dpp_add<0x142>(v);
            v = dpp_add<0x143>(v);
            zp = v;
        }
        if (lane == 63) {
            #pragma unroll
            for (int o = 0; o < 16; ++o) red[wid][o] = sp[o];
            red[wid][16] = zp;
        }
        __syncthreads();

        if (t < 16) {
            float tot = 0.f, Zt = 0.f;
            #pragma unroll
            for (int w2 = 0; w2 < 6; ++w2) { tot += red[w2][t]; Zt += red[w2][16]; }
            const float so = tot / Zt;
            float sq = so * so;
            #pragma unroll
            for (int off = 8; off >= 1; off >>= 1) sq += __shfl_xor(sq, off);
            const float fac = sqrtf(sq) / (1.f + sq);
            const float vo  = so * fac;
            if (it == 2) out[((size_t)bid << 4) + t] = vo;
            else         vfin[t] = vo;
        }
        if (it < 2) {
            __syncthreads();
            #pragma unroll
            for (int o = 0; o < 16; ++o) vprev[o] = vfin[o];
        }
    }
}

extern "C" void kernel_launch(void* const* d_in, const int* in_sizes, int n_in,
                              void* d_out, int out_size, void* d_ws, size_t ws_size,
                              hipStream_t stream)
{
    const float* x   = (const float*)d_in[0];
    const float* W   = (const float*)d_in[1];
    float*       out = (float*)d_out;
    const size_t WH_BYTES = (size_t)10 * RB * NCHUNK * 64 * sizeof(uint4);  // 2.95 MB

    if (ws_size >= WH_BYTES) {
        uint4* Wh = (uint4*)d_ws;
        convert_w<<<dim3(720), dim3(256), 0, stream>>>(W, Wh);
        capsule_routing_reg2<<<dim3(10 * 128), dim3(NB), 0, stream>>>(x, Wh, out);
    } else {
        capsule_routing_lds<<<dim3(10 * 256), dim3(NB), 0, stream>>>(x, W, out);
    }
}

// Round 13
// 162.873 us; speedup vs baseline: 1.1679x; 1.1640x over previous
//
#include <hip/hip_runtime.h>
#include <hip/hip_fp16.h>

#define NB     384           // 6 waves; 1152 = 384*3 -> 3 rows/thread
#define ROWS   3
#define N_ROUTE 1152
#define RB     18            // row-blocks of 64 rows
#define NCHUNK 16            // uint4 chunks per row in Wh layout

typedef __fp16 half2v __attribute__((ext_vector_type(2)));

__device__ __forceinline__ float fdot2u(unsigned int a, unsigned int b, float c) {
#if __has_builtin(__builtin_amdgcn_fdot2)
    half2v ha, hb;
    __builtin_memcpy(&ha, &a, 4);
    __builtin_memcpy(&hb, &b, 4);
    return __builtin_amdgcn_fdot2(ha, hb, c, false);
#else
    const __half2 h_a = *reinterpret_cast<const __half2*>(&a);
    const __half2 h_b = *reinterpret_cast<const __half2*>(&b);
    return fmaf(__low2float(h_a), __low2float(h_b),
           fmaf(__high2float(h_a), __high2float(h_b), c));
#endif
}

__device__ __forceinline__ unsigned int pkh(float a, float b) {
    half2v h = __builtin_amdgcn_cvt_pkrtz(a, b);
    unsigned int u;
    __builtin_memcpy(&u, &h, 4);
    return u;
}

template<int CTRL>
__device__ __forceinline__ float dpp_add(float v) {
    int t = __builtin_amdgcn_update_dpp(0, __float_as_int(v), CTRL, 0xF, 0xF, true);
    return v + __int_as_float(t);
}
// 4-step DPP: per-16-lane-group sums land in lanes 15/31/47/63.
__device__ __forceinline__ float wave_sum15(float v) {
    v = dpp_add<0x111>(v);   // row_shr:1
    v = dpp_add<0x112>(v);   // row_shr:2
    v = dpp_add<0x114>(v);   // row_shr:4
    v = dpp_add<0x118>(v);   // row_shr:8
    return v;
}

// ---- Pre-pass: W fp32 -> fp16, per-thread-coalesced layout ----
// Wh[((c*18+r)*16 + o)*64 + l] = uint4 of 4 half2 i-pairs of W[c][r*64+l][i][o].
__global__ __launch_bounds__(256, 4)
void convert_w(const float* __restrict__ W, uint4* __restrict__ Wh)
{
    const int tid  = blockIdx.x * 256 + threadIdx.x;   // 184320 = 180*64*16
    const int o    = tid & 15;
    const int rest = tid >> 4;
    const int l    = rest & 63;
    const int cr   = rest >> 6;                        // c*18 + r
    const float* __restrict__ src = W + ((size_t)cr * 64 + l) * 128 + o;
    float f[8];
    #pragma unroll
    for (int i = 0; i < 8; ++i) f[i] = src[i * 16];
    uint4 v;
    v.x = pkh(f[0], f[1]);
    v.y = pkh(f[2], f[3]);
    v.z = pkh(f[4], f[5]);
    v.w = pkh(f[6], f[7]);
    Wh[((size_t)cr * 16 + o) * 64 + l] = v;
}

// ---- Main kernel: register-P, 2 batches per block (one W read, 2x compute) ----
// amdgpu_waves_per_eu(2,2): pin allocator target at 2 waves/EU (256-VGPR
// budget) -- R11/R12 showed the default heuristic pins 128 VGPR (4 waves/EU)
// and spills the ~150-reg working set (WRITE_SIZE 161MB) regardless of
// __launch_bounds__ min-arg. sched_barrier(0) between phases stops the
// scheduler interleaving the two bt-passes (halves peak live sp[] ranges).
__global__
__attribute__((amdgpu_flat_work_group_size(NB, NB), amdgpu_waves_per_eu(2, 2)))
void capsule_routing_reg2(const float* __restrict__ x,
                          const uint4* __restrict__ Wh,
                          float* __restrict__ out)
{
    __shared__ float red[6][4][36];   // [wave][quad][bt*18 + (16 s, Z)]
    __shared__ float vfin[2][16];

    const int t    = threadIdx.x;
    const int lane = t & 63;
    const int wid  = t >> 6;
    const int bid  = blockIdx.x;
    const int c    = bid >> 7;
    const int b0   = (bid & 127) << 1;     // batches b0, b0+1

    // ---- P-build: rows n = 64*(wid+6k)+lane; one W read feeds both batches ----
    unsigned int p2[2][ROWS][8];
    {
        const float* __restrict__ xA = x + (size_t)b0 * (N_ROUTE * 8);
        const float* __restrict__ xB = xA + N_ROUTE * 8;
        const uint4* __restrict__ Wc = Wh + (size_t)c * RB * NCHUNK * 64;
        #pragma unroll
        for (int k = 0; k < ROWS; ++k) {
            const int r = wid + 6 * k;
            const int n = (r << 6) + lane;
            const float4 a0 = *reinterpret_cast<const float4*>(xA + n * 8);
            const float4 a1 = *reinterpret_cast<const float4*>(xA + n * 8 + 4);
            const float4 c0 = *reinterpret_cast<const float4*>(xB + n * 8);
            const float4 c1 = *reinterpret_cast<const float4*>(xB + n * 8 + 4);
            const unsigned int xhA[4] = { pkh(a0.x, a0.y), pkh(a0.z, a0.w),
                                          pkh(a1.x, a1.y), pkh(a1.z, a1.w) };
            const unsigned int xhB[4] = { pkh(c0.x, c0.y), pkh(c0.z, c0.w),
                                          pkh(c1.x, c1.y), pkh(c1.z, c1.w) };
            const uint4* __restrict__ wr = Wc + (size_t)r * NCHUNK * 64 + lane;
            #pragma unroll
            for (int j = 0; j < 8; ++j) {          // o-pair (2j, 2j+1)
                const uint4 w0 = wr[(2 * j)     * 64];
                const uint4 w1 = wr[(2 * j + 1) * 64];
                float dA0 = fdot2u(xhA[0], w0.x, 0.f);
                dA0 = fdot2u(xhA[1], w0.y, dA0);
                dA0 = fdot2u(xhA[2], w0.z, dA0);
                dA0 = fdot2u(xhA[3], w0.w, dA0);
                float dA1 = fdot2u(xhA[0], w1.x, 0.f);
                dA1 = fdot2u(xhA[1], w1.y, dA1);
                dA1 = fdot2u(xhA[2], w1.z, dA1);
                dA1 = fdot2u(xhA[3], w1.w, dA1);
                float dB0 = fdot2u(xhB[0], w0.x, 0.f);
                dB0 = fdot2u(xhB[1], w0.y, dB0);
                dB0 = fdot2u(xhB[2], w0.z, dB0);
                dB0 = fdot2u(xhB[3], w0.w, dB0);
                float dB1 = fdot2u(xhB[0], w1.x, 0.f);
                dB1 = fdot2u(xhB[1], w1.y, dB1);
                dB1 = fdot2u(xhB[2], w1.z, dB1);
                dB1 = fdot2u(xhB[3], w1.w, dB1);
                p2[0][k][j] = pkh(dA0, dA1);
                p2[1][k][j] = pkh(dB0, dB1);
            }
        }
    }
    __builtin_amdgcn_sched_barrier(0);     // end P-build: don't mix into routing

    float lg[2][ROWS] = {{0.f, 0.f, 0.f}, {0.f, 0.f, 0.f}};
    unsigned int vph[2][8] = {{0,0,0,0,0,0,0,0}, {0,0,0,0,0,0,0,0}};

    #pragma unroll
    for (int it = 0; it < 3; ++it) {
        // bt-sequential rows-pass + reduce (sched_barrier: keep live sets apart)
        #pragma unroll
        for (int bt = 0; bt < 2; ++bt) {
            float sp[16];
            #pragma unroll
            for (int o = 0; o < 16; ++o) sp[o] = 0.f;
            float zp = (it == 0) ? (float)ROWS : 0.f;

            #pragma unroll
            for (int k = 0; k < ROWS; ++k) {
                float e;
                if (it == 0) {
                    e = 1.f;                        // softmax of zeros = uniform
                } else {
                    float d = 0.f;                  // logit += dot(P[n], v)
                    #pragma unroll
                    for (int j = 0; j < 8; ++j) d = fdot2u(p2[bt][k][j], vph[bt][j], d);
                    lg[bt][k] += d;
                    e = __expf(lg[bt][k]);          // |lg| small; no max-sub
                    zp += e;
                }
                #pragma unroll
                for (int j = 0; j < 8; ++j) {
                    const __half2 h = *reinterpret_cast<const __half2*>(&p2[bt][k][j]);
                    sp[2 * j]     = fmaf(e, __low2float(h),  sp[2 * j]);
                    sp[2 * j + 1] = fmaf(e, __high2float(h), sp[2 * j + 1]);
                }
            }

            // 17-value 4-step DPP: 16-lane group sums in lanes 15 mod 16
            #pragma unroll
            for (int o = 0; o < 16; ++o) sp[o] = wave_sum15(sp[o]);
            zp = wave_sum15(zp);
            if ((lane & 15) == 15) {
                const int q = lane >> 4;
                #pragma unroll
                for (int o = 0; o < 16; ++o) red[wid][q][bt * 18 + o] = sp[o];
                red[wid][q][bt * 18 + 16] = zp;
            }
            __builtin_amdgcn_sched_barrier(0);      // bt phases stay disjoint
        }
        __syncthreads();                            // barrier 1: red ready

        if (t < 32) {                               // t<16: bt0, t in 16..31: bt1
            const int bt = t >> 4, o = t & 15;
            float tot = 0.f, Zt = 0.f;
            #pragma unroll
            for (int w2 = 0; w2 < 6; ++w2)
                #pragma unroll
                for (int q = 0; q < 4; ++q) {
                    tot += red[w2][q][bt * 18 + o];
                    Zt  += red[w2][q][bt * 18 + 16];
                }
            const float so = tot / Zt;              // s[o]
            float sq = so * so;                     // 16-lane ||s||^2
            #pragma unroll
            for (int off = 8; off >= 1; off >>= 1) sq += __shfl_xor(sq, off, 16);
            const float fac = sqrtf(sq) / (1.f + sq);
            const float vo  = so * fac;
            if (it == 2) out[(((size_t)c << 8) + b0 + bt) * 16 + o] = vo;
            else         vfin[bt][o] = vo;
        }
        if (it < 2) {
            __syncthreads();                        // barrier 2: vfin ready, red safe
            #pragma unroll
            for (int bt = 0; bt < 2; ++bt) {
                const float4 v0 = *reinterpret_cast<const float4*>(&vfin[bt][0]);
                const float4 v1 = *reinterpret_cast<const float4*>(&vfin[bt][4]);
                const float4 v2 = *reinterpret_cast<const float4*>(&vfin[bt][8]);
                const float4 v3 = *reinterpret_cast<const float4*>(&vfin[bt][12]);
                vph[bt][0] = pkh(v0.x, v0.y);  vph[bt][1] = pkh(v0.z, v0.w);
                vph[bt][2] = pkh(v1.x, v1.y);  vph[bt][3] = pkh(v1.z, v1.w);
                vph[bt][4] = pkh(v2.x, v2.y);  vph[bt][5] = pkh(v2.z, v2.w);
                vph[bt][6] = pkh(v3.x, v3.y);  vph[bt][7] = pkh(v3.z, v3.w);
            }
        }
    }
}

// ---- Fallback (ws too small): R8-style fp32-W + LDS-P kernel (known-good) ----
__global__ __launch_bounds__(NB, 2)
void capsule_routing_lds(const float* __restrict__ x,
                         const float* __restrict__ W,
                         float* __restrict__ out)
{
    __shared__ unsigned int P[N_ROUTE * 8];
    __shared__ float red[6][20];
    __shared__ float vfin[16];

    const int t    = threadIdx.x;
    const int bid  = blockIdx.x;
    const int c    = bid >> 8;
    const int b    = bid & 255;
    const int lane = t & 63;
    const int wid  = t >> 6;

    {
        const int og = t & 3;
        const int nl = t >> 2;
        const float* __restrict__ xb = x + (size_t)b * (N_ROUTE * 8);
        const float* __restrict__ Wc = W + (size_t)c * (N_ROUTE * 128);
        #pragma unroll 2
        for (int pp = 0; pp < 12; ++pp) {
            const int n = pp * 96 + nl;
            const float4 x0 = *reinterpret_cast<const float4*>(xb + n * 8);
            const float4 x1 = *reinterpret_cast<const float4*>(xb + n * 8 + 4);
            const float xs[8] = {x0.x, x0.y, x0.z, x0.w, x1.x, x1.y, x1.z, x1.w};
            const float* __restrict__ wp = Wc + (size_t)n * 128 + (og << 2);
            float4 acc = make_float4(0.f, 0.f, 0.f, 0.f);
            #pragma unroll
            for (int i = 0; i < 8; ++i) {
                const float4 w = *reinterpret_cast<const float4*>(wp + i * 16);
                acc.x = fmaf(xs[i], w.x, acc.x);
                acc.y = fmaf(xs[i], w.y, acc.y);
                acc.z = fmaf(xs[i], w.z, acc.z);
                acc.w = fmaf(xs[i], w.w, acc.w);
            }
            const int s    = (n >> 2) & 7;
            const int base = n << 3;
            P[base + (((og << 1)    ) ^ s)] = pkh(acc.x, acc.y);
            P[base + (((og << 1) + 1) ^ s)] = pkh(acc.z, acc.w);
        }
    }
    __syncthreads();

    float vprev[16];
    #pragma unroll
    for (int o = 0; o < 16; ++o) vprev[o] = 0.f;
    float lg[ROWS] = {0.f, 0.f, 0.f};

    #pragma unroll
    for (int it = 0; it < 3; ++it) {
        float sp[16];
        #pragma unroll
        for (int o = 0; o < 16; ++o) sp[o] = 0.f;
        float zp = (it == 0) ? (float)ROWS : 0.f;

        #pragma unroll
        for (int k = 0; k < ROWS; ++k) {
            const int n = t + k * NB;
            const int s = (n >> 2) & 7;
            const unsigned int* __restrict__ pr = &P[n << 3];
            __half2 h[8];
            #pragma unroll
            for (int j = 0; j < 8; ++j) {
                const unsigned int w = pr[j ^ s];
                h[j] = *reinterpret_cast<const __half2*>(&w);
            }
            float e;
            if (it == 0) {
                e = 1.f;
            } else {
                float d = 0.f;
                #pragma unroll
                for (int j = 0; j < 8; ++j) {
                    d = fmaf(__low2float(h[j]),  vprev[2 * j],     d);
                    d = fmaf(__high2float(h[j]), vprev[2 * j + 1], d);
                }
                lg[k] += d;
                e = __expf(lg[k]);
                zp += e;
            }
            #pragma unroll
            for (int j = 0; j < 8; ++j) {
                sp[2 * j]     = fmaf(e, __low2float(h[j]),  sp[2 * j]);
                sp[2 * j + 1] = fmaf(e, __high2float(h[j]), sp[2 * j + 1]);
            }
        }

        #pragma unroll
        for (int o = 0; o < 16; ++o) {
            float v = wave_sum15(sp[o]);
            v = dpp_add<0x142>(v);          // row_bcast:15
            v = dpp_add<0x143>(v);          // row_bcast:31
            sp[o] = v;
        }
        {
            float v = wave_sum15(zp);
            v = dpp_add<0x142>(v);
            v = dpp_add<0x143>(v);
            zp = v;
        }
        if (lane == 63) {
            #pragma unroll
            for (int o = 0; o < 16; ++o) red[wid][o] = sp[o];
            red[wid][16] = zp;
        }
        __syncthreads();

        if (t < 16) {
            float tot = 0.f, Zt = 0.f;
            #pragma unroll
            for (int w2 = 0; w2 < 6; ++w2) { tot += red[w2][t]; Zt += red[w2][16]; }
            const float so = tot / Zt;
            float sq = so * so;
            #pragma unroll
            for (int off = 8; off >= 1; off >>= 1) sq += __shfl_xor(sq, off);
            const float fac = sqrtf(sq) / (1.f + sq);
            const float vo  = so * fac;
            if (it == 2) out[((size_t)bid << 4) + t] = vo;
            else         vfin[t] = vo;
        }
        if (it < 2) {
            __syncthreads();
            #pragma unroll
            for (int o = 0; o < 16; ++o) vprev[o] = vfin[o];
        }
    }
}

extern "C" void kernel_launch(void* const* d_in, const int* in_sizes, int n_in,
                              void* d_out, int out_size, void* d_ws, size_t ws_size,
                              hipStream_t stream)
{
    const float* x   = (const float*)d_in[0];
    const float* W   = (const float*)d_in[1];
    float*       out = (float*)d_out;
    const size_t WH_BYTES = (size_t)10 * RB * NCHUNK * 64 * sizeof(uint4);  // 2.95 MB

    if (ws_size >= WH_BYTES) {
        uint4* Wh = (uint4*)d_ws;
        convert_w<<<dim3(720), dim3(256), 0, stream>>>(W, Wh);
        capsule_routing_reg2<<<dim3(10 * 128), dim3(NB), 0, stream>>>(x, Wh, out);
    } else {
        capsule_routing_lds<<<dim3(10 * 256), dim3(NB), 0, stream>>>(x, W, out);
    }
}

// Round 14
// 144.117 us; speedup vs baseline: 1.3199x; 1.1301x over previous
//
#include <hip/hip_runtime.h>
#include <hip/hip_fp16.h>

#define NB     384           // 6 waves; 1152 = 384*3 -> 3 rows/thread
#define ROWS   3
#define N_ROUTE 1152
#define RB     18            // row-blocks of 64 rows
#define NCHUNK 16            // uint4 chunks per row in Wh layout

typedef __fp16 half2v __attribute__((ext_vector_type(2)));

__device__ __forceinline__ float fdot2u(unsigned int a, unsigned int b, float c) {
#if __has_builtin(__builtin_amdgcn_fdot2)
    half2v ha, hb;
    __builtin_memcpy(&ha, &a, 4);
    __builtin_memcpy(&hb, &b, 4);
    return __builtin_amdgcn_fdot2(ha, hb, c, false);
#else
    const __half2 h_a = *reinterpret_cast<const __half2*>(&a);
    const __half2 h_b = *reinterpret_cast<const __half2*>(&b);
    return fmaf(__low2float(h_a), __low2float(h_b),
           fmaf(__high2float(h_a), __high2float(h_b), c));
#endif
}

__device__ __forceinline__ unsigned int pkh(float a, float b) {
    half2v h = __builtin_amdgcn_cvt_pkrtz(a, b);
    unsigned int u;
    __builtin_memcpy(&u, &h, 4);
    return u;
}

template<int CTRL>
__device__ __forceinline__ float dpp_add(float v) {
    int t = __builtin_amdgcn_update_dpp(0, __float_as_int(v), CTRL, 0xF, 0xF, true);
    return v + __int_as_float(t);
}
// 4-step DPP: per-16-lane-group sums land in lanes 15/31/47/63.
__device__ __forceinline__ float wave_sum15(float v) {
    v = dpp_add<0x111>(v);   // row_shr:1
    v = dpp_add<0x112>(v);   // row_shr:2
    v = dpp_add<0x114>(v);   // row_shr:4
    v = dpp_add<0x118>(v);   // row_shr:8
    return v;
}

// ---- Pre-pass: W fp32 -> fp16, per-thread-coalesced layout ----
// Wh[((c*18+r)*16 + o)*64 + l] = uint4 of 4 half2 i-pairs of W[c][r*64+l][i][o].
__global__ __launch_bounds__(256, 4)
void convert_w(const float* __restrict__ W, uint4* __restrict__ Wh)
{
    const int tid  = blockIdx.x * 256 + threadIdx.x;   // 184320 = 180*64*16
    const int o    = tid & 15;
    const int rest = tid >> 4;
    const int l    = rest & 63;
    const int cr   = rest >> 6;                        // c*18 + r
    const float* __restrict__ src = W + ((size_t)cr * 64 + l) * 128 + o;
    float f[8];
    #pragma unroll
    for (int i = 0; i < 8; ++i) f[i] = src[i * 16];
    uint4 v;
    v.x = pkh(f[0], f[1]);
    v.y = pkh(f[2], f[3]);
    v.z = pkh(f[4], f[5]);
    v.w = pkh(f[6], f[7]);
    Wh[((size_t)cr * 16 + o) * 64 + l] = v;
}

// ---- Main kernel: register-P, 2 batches per block (one W read, 2x compute) ----
// Spill root-cause (R11-R13): the fully-unrolled P-build hoists all 16 W-chunk
// loads per k (64 VGPR in flight) on top of p2(48) -> peak ~130 > the
// allocator's 128 target -> spill-for-occupancy. Fix: sched_barrier(0) every
// 2nd j-iteration caps in-flight W at ~16 regs; peak ~105 fits 128 natively.
__global__ __launch_bounds__(NB, 2)
void capsule_routing_reg2(const float* __restrict__ x,
                          const uint4* __restrict__ Wh,
                          float* __restrict__ out)
{
    __shared__ float red[6][4][36];   // [wave][quad][bt*18 + (16 s, Z)]
    __shared__ float vfin[2][16];

    const int t    = threadIdx.x;
    const int lane = t & 63;
    const int wid  = t >> 6;
    const int bid  = blockIdx.x;
    const int c    = bid >> 7;
    const int b0   = (bid & 127) << 1;     // batches b0, b0+1

    // ---- P-build: rows n = 64*(wid+6k)+lane; one W read feeds both batches ----
    unsigned int p2[2][ROWS][8];
    {
        const float* __restrict__ xA = x + (size_t)b0 * (N_ROUTE * 8);
        const float* __restrict__ xB = xA + N_ROUTE * 8;
        const uint4* __restrict__ Wc = Wh + (size_t)c * RB * NCHUNK * 64;
        #pragma unroll
        for (int k = 0; k < ROWS; ++k) {
            const int r = wid + 6 * k;
            const int n = (r << 6) + lane;
            const float4 a0 = *reinterpret_cast<const float4*>(xA + n * 8);
            const float4 a1 = *reinterpret_cast<const float4*>(xA + n * 8 + 4);
            const float4 c0 = *reinterpret_cast<const float4*>(xB + n * 8);
            const float4 c1 = *reinterpret_cast<const float4*>(xB + n * 8 + 4);
            const unsigned int xhA[4] = { pkh(a0.x, a0.y), pkh(a0.z, a0.w),
                                          pkh(a1.x, a1.y), pkh(a1.z, a1.w) };
            const unsigned int xhB[4] = { pkh(c0.x, c0.y), pkh(c0.z, c0.w),
                                          pkh(c1.x, c1.y), pkh(c1.z, c1.w) };
            const uint4* __restrict__ wr = Wc + (size_t)r * NCHUNK * 64 + lane;
            #pragma unroll
            for (int j = 0; j < 8; ++j) {          // o-pair (2j, 2j+1)
                const uint4 w0 = wr[(2 * j)     * 64];
                const uint4 w1 = wr[(2 * j + 1) * 64];
                float dA0 = fdot2u(xhA[0], w0.x, 0.f);
                dA0 = fdot2u(xhA[1], w0.y, dA0);
                dA0 = fdot2u(xhA[2], w0.z, dA0);
                dA0 = fdot2u(xhA[3], w0.w, dA0);
                float dA1 = fdot2u(xhA[0], w1.x, 0.f);
                dA1 = fdot2u(xhA[1], w1.y, dA1);
                dA1 = fdot2u(xhA[2], w1.z, dA1);
                dA1 = fdot2u(xhA[3], w1.w, dA1);
                float dB0 = fdot2u(xhB[0], w0.x, 0.f);
                dB0 = fdot2u(xhB[1], w0.y, dB0);
                dB0 = fdot2u(xhB[2], w0.z, dB0);
                dB0 = fdot2u(xhB[3], w0.w, dB0);
                float dB1 = fdot2u(xhB[0], w1.x, 0.f);
                dB1 = fdot2u(xhB[1], w1.y, dB1);
                dB1 = fdot2u(xhB[2], w1.z, dB1);
                dB1 = fdot2u(xhB[3], w1.w, dB1);
                p2[0][k][j] = pkh(dA0, dA1);
                p2[1][k][j] = pkh(dB0, dB1);
                if ((j & 1) == 1)
                    __builtin_amdgcn_sched_barrier(0);  // cap W-load look-ahead
            }
        }
    }
    __builtin_amdgcn_sched_barrier(0);     // end P-build: don't mix into routing

    float lg[2][ROWS] = {{0.f, 0.f, 0.f}, {0.f, 0.f, 0.f}};
    unsigned int vph[2][8] = {{0,0,0,0,0,0,0,0}, {0,0,0,0,0,0,0,0}};

    #pragma unroll
    for (int it = 0; it < 3; ++it) {
        // bt-sequential rows-pass + reduce (keeps the two live sets disjoint)
        #pragma unroll
        for (int bt = 0; bt < 2; ++bt) {
            float sp[16];
            #pragma unroll
            for (int o = 0; o < 16; ++o) sp[o] = 0.f;
            float zp = (it == 0) ? (float)ROWS : 0.f;

            #pragma unroll
            for (int k = 0; k < ROWS; ++k) {
                float e;
                if (it == 0) {
                    e = 1.f;                        // softmax of zeros = uniform
                } else {
                    float d = 0.f;                  // logit += dot(P[n], v)
                    #pragma unroll
                    for (int j = 0; j < 8; ++j) d = fdot2u(p2[bt][k][j], vph[bt][j], d);
                    lg[bt][k] += d;
                    e = __expf(lg[bt][k]);          // |lg| small; no max-sub
                    zp += e;
                }
                #pragma unroll
                for (int j = 0; j < 8; ++j) {
                    const __half2 h = *reinterpret_cast<const __half2*>(&p2[bt][k][j]);
                    sp[2 * j]     = fmaf(e, __low2float(h),  sp[2 * j]);
                    sp[2 * j + 1] = fmaf(e, __high2float(h), sp[2 * j + 1]);
                }
            }

            // 17-value 4-step DPP: 16-lane group sums in lanes 15 mod 16
            #pragma unroll
            for (int o = 0; o < 16; ++o) sp[o] = wave_sum15(sp[o]);
            zp = wave_sum15(zp);
            if ((lane & 15) == 15) {
                const int q = lane >> 4;
                #pragma unroll
                for (int o = 0; o < 16; ++o) red[wid][q][bt * 18 + o] = sp[o];
                red[wid][q][bt * 18 + 16] = zp;
            }
            __builtin_amdgcn_sched_barrier(0);      // bt phases stay disjoint
        }
        __syncthreads();                            // barrier 1: red ready

        if (t < 32) {                               // t<16: bt0, t in 16..31: bt1
            const int bt = t >> 4, o = t & 15;
            float tot = 0.f, Zt = 0.f;
            #pragma unroll
            for (int w2 = 0; w2 < 6; ++w2)
                #pragma unroll
                for (int q = 0; q < 4; ++q) {
                    tot += red[w2][q][bt * 18 + o];
                    Zt  += red[w2][q][bt * 18 + 16];
                }
            const float so = tot / Zt;              // s[o]
            float sq = so * so;                     // 16-lane ||s||^2
            #pragma unroll
            for (int off = 8; off >= 1; off >>= 1) sq += __shfl_xor(sq, off, 16);
            const float fac = sqrtf(sq) / (1.f + sq);
            const float vo  = so * fac;
            if (it == 2) out[(((size_t)c << 8) + b0 + bt) * 16 + o] = vo;
            else         vfin[bt][o] = vo;
        }
        if (it < 2) {
            __syncthreads();                        // barrier 2: vfin ready, red safe
            #pragma unroll
            for (int bt = 0; bt < 2; ++bt) {
                const float4 v0 = *reinterpret_cast<const float4*>(&vfin[bt][0]);
                const float4 v1 = *reinterpret_cast<const float4*>(&vfin[bt][4]);
                const float4 v2 = *reinterpret_cast<const float4*>(&vfin[bt][8]);
                const float4 v3 = *reinterpret_cast<const float4*>(&vfin[bt][12]);
                vph[bt][0] = pkh(v0.x, v0.y);  vph[bt][1] = pkh(v0.z, v0.w);
                vph[bt][2] = pkh(v1.x, v1.y);  vph[bt][3] = pkh(v1.z, v1.w);
                vph[bt][4] = pkh(v2.x, v2.y);  vph[bt][5] = pkh(v2.z, v2.w);
                vph[bt][6] = pkh(v3.x, v3.y);  vph[bt][7] = pkh(v3.z, v3.w);
            }
        }
    }
}

// ---- Fallback (ws too small): R8-style fp32-W + LDS-P kernel (known-good) ----
__global__ __launch_bounds__(NB, 2)
void capsule_routing_lds(const float* __restrict__ x,
                         const float* __restrict__ W,
                         float* __restrict__ out)
{
    __shared__ unsigned int P[N_ROUTE * 8];
    __shared__ float red[6][20];
    __shared__ float vfin[16];

    const int t    = threadIdx.x;
    const int bid  = blockIdx.x;
    const int c    = bid >> 8;
    const int b    = bid & 255;
    const int lane = t & 63;
    const int wid  = t >> 6;

    {
        const int og = t & 3;
        const int nl = t >> 2;
        const float* __restrict__ xb = x + (size_t)b * (N_ROUTE * 8);
        const float* __restrict__ Wc = W + (size_t)c * (N_ROUTE * 128);
        #pragma unroll 2
        for (int pp = 0; pp < 12; ++pp) {
            const int n = pp * 96 + nl;
            const float4 x0 = *reinterpret_cast<const float4*>(xb + n * 8);
            const float4 x1 = *reinterpret_cast<const float4*>(xb + n * 8 + 4);
            const float xs[8] = {x0.x, x0.y, x0.z, x0.w, x1.x, x1.y, x1.z, x1.w};
            const float* __restrict__ wp = Wc + (size_t)n * 128 + (og << 2);
            float4 acc = make_float4(0.f, 0.f, 0.f, 0.f);
            #pragma unroll
            for (int i = 0; i < 8; ++i) {
                const float4 w = *reinterpret_cast<const float4*>(wp + i * 16);
                acc.x = fmaf(xs[i], w.x, acc.x);
                acc.y = fmaf(xs[i], w.y, acc.y);
                acc.z = fmaf(xs[i], w.z, acc.z);
                acc.w = fmaf(xs[i], w.w, acc.w);
            }
            const int s    = (n >> 2) & 7;
            const int base = n << 3;
            P[base + (((og << 1)    ) ^ s)] = pkh(acc.x, acc.y);
            P[base + (((og << 1) + 1) ^ s)] = pkh(acc.z, acc.w);
        }
    }
    __syncthreads();

    float vprev[16];
    #pragma unroll
    for (int o = 0; o < 16; ++o) vprev[o] = 0.f;
    float lg[ROWS] = {0.f, 0.f, 0.f};

    #pragma unroll
    for (int it = 0; it < 3; ++it) {
        float sp[16];
        #pragma unroll
        for (int o = 0; o < 16; ++o) sp[o] = 0.f;
        float zp = (it == 0) ? (float)ROWS : 0.f;

        #pragma unroll
        for (int k = 0; k < ROWS; ++k) {
            const int n = t + k * NB;
            const int s = (n >> 2) & 7;
            const unsigned int* __restrict__ pr = &P[n << 3];
            __half2 h[8];
            #pragma unroll
            for (int j = 0; j < 8; ++j) {
                const unsigned int w = pr[j ^ s];
                h[j] = *reinterpret_cast<const __half2*>(&w);
            }
            float e;
            if (it == 0) {
                e = 1.f;
            } else {
                float d = 0.f;
                #pragma unroll
                for (int j = 0; j < 8; ++j) {
                    d = fmaf(__low2float(h[j]),  vprev[2 * j],     d);
                    d = fmaf(__high2float(h[j]), vprev[2 * j + 1], d);
                }
                lg[k] += d;
                e = __expf(lg[k]);
                zp += e;
            }
            #pragma unroll
            for (int j = 0; j < 8; ++j) {
                sp[2 * j]     = fmaf(e, __low2float(h[j]),  sp[2 * j]);
                sp[2 * j + 1] = fmaf(e, __high2float(h[j]), sp[2 * j + 1]);
            }
        }

        #pragma unroll
        for (int o = 0; o < 16; ++o) {
            float v = wave_sum15(sp[o]);
            v = dpp_add<0x142>(v);          // row_bcast:15
            v = dpp_add<0x143>(v);          // row_bcast:31
            sp[o] = v;
        }
        {
            float v = wave_sum15(zp);
            v = dpp_add<0x142>(v);
            v = dpp_add<0x143>(v);
            zp = v;
        }
        if (lane == 63) {
            #pragma unroll
            for (int o = 0; o < 16; ++o) red[wid][o] = sp[o];
            red[wid][16] = zp;
        }
        __syncthreads();

        if (t < 16) {
            float tot = 0.f, Zt = 0.f;
            #pragma unroll
            for (int w2 = 0; w2 < 6; ++w2) { tot += red[w2][t]; Zt += red[w2][16]; }
            const float so = tot / Zt;
            float sq = so * so;
            #pragma unroll
            for (int off = 8; off >= 1; off >>= 1) sq += __shfl_xor(sq, off);
            const float fac = sqrtf(sq) / (1.f + sq);
            const float vo  = so * fac;
            if (it == 2) out[((size_t)bid << 4) + t] = vo;
            else         vfin[t] = vo;
        }
        if (it < 2) {
            __syncthreads();
            #pragma unroll
            for (int o = 0; o < 16; ++o) vprev[o] = vfin[o];
        }
    }
}

extern "C" void kernel_launch(void* const* d_in, const int* in_sizes, int n_in,
                              void* d_out, int out_size, void* d_ws, size_t ws_size,
                              hipStream_t stream)
{
    const float* x   = (const float*)d_in[0];
    const float* W   = (const float*)d_in[1];
    float*       out = (float*)d_out;
    const size_t WH_BYTES = (size_t)10 * RB * NCHUNK * 64 * sizeof(uint4);  // 2.95 MB

    if (ws_size >= WH_BYTES) {
        uint4* Wh = (uint4*)d_ws;
        convert_w<<<dim3(720), dim3(256), 0, stream>>>(W, Wh);
        capsule_routing_reg2<<<dim3(10 * 128), dim3(NB), 0, stream>>>(x, Wh, out);
    } else {
        capsule_routing_lds<<<dim3(10 * 256), dim3(NB), 0, stream>>>(x, W, out);
    }
}